// Round 7
// baseline (35683.392 us; speedup 1.0000x reference)
//
#include <hip/hip_runtime.h>

#define LSEQ 8128
#define NB 8
#define CORR_CAP 8192
#define RINGSZ 1024
#define FLAG_R0 0
#define FLAG_H0 32
#define FLAG_H1 64
#define PROG_R1 96

typedef __attribute__((ext_vector_type(8))) short short8;
typedef __attribute__((ext_vector_type(4))) float float4e;
typedef __attribute__((ext_vector_type(4))) int int4v;

#define MFMA16(a,b,c) __builtin_amdgcn_mfma_f32_16x16x32_bf16((a),(b),(c),0,0,0)
#define MFMAI8(a,b,c) __builtin_amdgcn_mfma_i32_16x16x64_i8((a),(b),(c),0,0,0)

// ---- workspace layout (bytes) ----
#define WS_P      4096ul
#define WS_AEE    528384ul
#define WS_VPN    536576ul      // bf16 swizzled [8128][1024]
#define WS_EIDX   17182720ul
#define WS_CORR   17444864ul    // bf16 swizzled [8192][1024]
#define WS_WQ0    34222080ul    // i8 [1024][256]
#define WS_SC0    34484224ul    // f32 [512] row-pair dequant
#define WS_WQ1    34488320ul
#define WS_SC1    34750464ul
#define WS_WQI    34754560ul
#define WS_SCI    35016704ul
#define WS_URING  35020800ul    // bf16 swizzled ring [1024][8][1024]
#define WS_H0I    51798016ul    // i8 [8129][8][256]
#define WS_H1W    68446208ul    // bf16 [8129][8][256]
// end ~101.7 MB

static __device__ __forceinline__ unsigned short f2bf(float f) {
  unsigned u = __float_as_uint(f);
  return (unsigned short)((u + 0x7fffu + ((u >> 16) & 1u)) >> 16);  // RNE
}
static __device__ __forceinline__ float blo(unsigned u) { return __uint_as_float(u << 16); }
static __device__ __forceinline__ float bhi(unsigned u) { return __uint_as_float(u & 0xffff0000u); }
static __device__ __forceinline__ float uph(unsigned u, int hi) { return hi ? bhi(u) : blo(u); }
static __device__ __forceinline__ short8 pack8f(const float* __restrict__ p) {
  short8 r;
#pragma unroll
  for (int i = 0; i < 8; ++i) r[i] = (short)f2bf(p[i]);
  return r;
}
static __device__ __forceinline__ unsigned aload(const unsigned* p) {
  return __hip_atomic_load(p, __ATOMIC_RELAXED, __HIP_MEMORY_SCOPE_AGENT);
}
static __device__ __forceinline__ unsigned long long aload64(const unsigned long long* p) {
  return __hip_atomic_load(p, __ATOMIC_RELAXED, __HIP_MEMORY_SCOPE_AGENT);
}
static __device__ __forceinline__ void astore(unsigned* p, unsigned v) {
  __hip_atomic_store(p, v, __ATOMIC_RELAXED, __HIP_MEMORY_SCOPE_AGENT);
}
static __device__ __forceinline__ void barrier_lgkm() {
  asm volatile("s_waitcnt lgkmcnt(0)\ns_barrier" ::: "memory");
}
static __device__ __forceinline__ float sigf(float x) { return 1.f / (1.f + __expf(-x)); }
static __device__ __forceinline__ float tanhf2(float x) { return 2.f / (1.f + __expf(-2.f * x)) - 1.f; }

// ---- P = W_ih0[:,128:192] @ ew_W2 ----
__global__ void k_prep_P(const float* __restrict__ Wih0, const float* __restrict__ ewW2,
                         float* __restrict__ P) {
  int idx = blockIdx.x * 256 + threadIdx.x;
  int g = idx >> 7, k = idx & 127;
  const float* wr = Wih0 + (size_t)g * 320 + 128;
  float s = 0.f;
#pragma unroll 8
  for (int j = 0; j < 64; ++j) s += wr[j] * ewW2[j * 128 + k];
  P[idx] = s;
}

__global__ void k_prep_aee(const float* __restrict__ Wih0, const float* __restrict__ ee,
                           const float* __restrict__ b1, const float* __restrict__ b2,
                           const float* __restrict__ P, float* __restrict__ aee) {
  int idx = blockIdx.x * 256 + threadIdx.x;  // < 2048
  int s = idx >> 10, g = idx & 1023;
  const float* wr = Wih0 + (size_t)g * 320;
  float a = 0.f;
#pragma unroll 8
  for (int i = 0; i < 128; ++i) a += wr[i] * ee[s * 128 + i];
#pragma unroll 8
  for (int j = 0; j < 64; ++j) a += wr[128 + j] * b2[j];
  const float* pr = P + (size_t)g * 128;
#pragma unroll 8
  for (int k = 0; k < 128; ++k) a += pr[k] * fmaxf(b1[k], 0.f);
  aee[s * 1024 + g] = a;
}

// slot -> gate-row swizzle: slot=(w,lk,grp,r), g = (grp>>1)*256 + (2w+(grp&1))*16 + lk*4 + r
static __device__ __forceinline__ int slot2g(int s) {
  int w = s >> 7, lk = (s >> 5) & 3, grp = (s >> 2) & 7, r = s & 3;
  return ((grp >> 1) << 8) + ((w * 2 + (grp & 1)) << 4) + (lk << 2) + r;
}

__global__ void k_prep_vpn(const float* __restrict__ Wih0, const float* __restrict__ nemb,
                           const float* __restrict__ aee, unsigned short* __restrict__ vpnsw) {
  __shared__ float pn[128];
  int t = blockIdx.x, tid = threadIdx.x;
  if (tid < 32) {
    float div = expf(-9.2103403719761836f * (float)(2 * tid) / 64.f);
    float ang = (float)t * div;
    pn[2 * tid] = sinf(ang);
    pn[2 * tid + 1] = cosf(ang);
  } else if (tid < 96) {
    int r = (int)((1.f + sqrtf(8.f * (float)t + 1.f)) * 0.5f);
    while (r * (r + 1) / 2 <= t) ++r;
    while (r * (r - 1) / 2 > t) --r;
    pn[64 + (tid - 32)] = nemb[r * 64 + (tid - 32)];
  }
  __syncthreads();
#pragma unroll
  for (int rr = 0; rr < 4; ++rr) {
    int slot = rr * 256 + tid;
    int g = slot2g(slot);
    const float* wr = Wih0 + (size_t)g * 320 + 192;
    float s = 0.f;
#pragma unroll 8
    for (int i = 0; i < 128; ++i) s += wr[i] * pn[i];
    vpnsw[(size_t)t * 1024 + slot] = f2bf(s + aee[g]);
  }
}

__global__ void k_prep_eidx(const float* __restrict__ xadj, int* __restrict__ eidx,
                            unsigned* __restrict__ counter) {
  int idx = blockIdx.x * 256 + threadIdx.x;
  if (idx >= NB * LSEQ) return;
  int t = idx % LSEQ;
  int e = -1;
  if (t > 0 && xadj[idx - 1] > 0.f) {
    e = (int)atomicAdd(counter, 1u);
    if (e >= CORR_CAP) e = -1;
  }
  eidx[idx] = e;
}

__global__ void k_prep_corr(const float* __restrict__ xadj, const float* __restrict__ w1,
                            const float* __restrict__ b1, const float* __restrict__ P,
                            const float* __restrict__ aee, const int* __restrict__ eidx,
                            unsigned short* __restrict__ corrsw) {
  __shared__ float rh[128];
  int bid = blockIdx.x;
  int e = eidx[bid];
  if (e < 0) return;
  int tid = threadIdx.x;
  float wt = xadj[bid - 1];
  if (tid < 128) {
    float bb = b1[tid];
    rh[tid] = fmaxf(wt * w1[tid] + bb, 0.f) - fmaxf(bb, 0.f);
  }
  __syncthreads();
#pragma unroll
  for (int rr = 0; rr < 4; ++rr) {
    int slot = rr * 256 + tid;
    int g = slot2g(slot);
    const float* pr = P + (size_t)g * 128;
    float s = 0.f;
#pragma unroll 8
    for (int k = 0; k < 128; ++k) s += pr[k] * rh[k];
    corrsw[(size_t)e * 1024 + slot] = f2bf(s + aee[1024 + g] - aee[g]);
  }
}

// ---- i8 quantize: one row-pair per block (64 threads), per-pair scale ----
__global__ void k_prep_qw(const float* __restrict__ Whh0, const float* __restrict__ Whh1,
                          const float* __restrict__ Wih1,
                          unsigned* __restrict__ q0, unsigned* __restrict__ q1,
                          unsigned* __restrict__ qi,
                          float* __restrict__ d0, float* __restrict__ d1,
                          float* __restrict__ di) {
  int pid = blockIdx.x;  // 0..1535
  int mtx = pid >> 9, pr = pid & 511;
  const float* src = (mtx == 0) ? Whh0 : (mtx == 1) ? Whh1 : Wih1;
  unsigned* qd = (mtx == 0) ? q0 : (mtx == 1) ? q1 : qi;
  float* dd = (mtx == 0) ? d0 : (mtx == 1) ? d1 : di;
  int t = threadIdx.x;
  int r0 = pr * 2;
  float a[4], b4[4];
  float mx = 0.f;
#pragma unroll
  for (int i = 0; i < 4; ++i) {
    a[i] = src[(size_t)r0 * 256 + t * 4 + i];
    b4[i] = src[(size_t)(r0 + 1) * 256 + t * 4 + i];
    mx = fmaxf(mx, fmaxf(fabsf(a[i]), fabsf(b4[i])));
  }
#pragma unroll
  for (int d2 = 1; d2 < 64; d2 <<= 1) mx = fmaxf(mx, __shfl_xor(mx, d2));
  mx = fmaxf(mx, 1e-20f);
  float inv = 127.f / mx;
  unsigned pa = 0, pb = 0;
#pragma unroll
  for (int i = 0; i < 4; ++i) {
    int qa = (int)rintf(a[i] * inv), qb = (int)rintf(b4[i] * inv);
    pa |= ((unsigned)(qa & 255)) << (8 * i);
    pb |= ((unsigned)(qb & 255)) << (8 * i);
  }
  qd[(size_t)r0 * 64 + t] = pa;
  qd[(size_t)(r0 + 1) * 64 + t] = pb;
  if (t == 0) dd[pr] = mx / 16129.f;  // = (mx/127)*(1/127)
}

// ============ persistent LSTM: WG0=L0, WG1=L1, WG2/3 = u producers ============
template <int LAYER>
static __device__ __forceinline__ void recur(
    const unsigned* __restrict__ wqg, const float* __restrict__ dqp,
    const unsigned short* __restrict__ vpnsw, const int* __restrict__ eidx,
    const unsigned short* __restrict__ corrsw, const unsigned long long* __restrict__ uring64,
    const float* __restrict__ inith, const float* __restrict__ initc,
    unsigned* flags, unsigned* hout, unsigned char* hT, int tid) {
  const int w = tid >> 6, l = tid & 63, lm = l & 15, lk = l >> 4, b = lm & 7;
  unsigned budget = 50000000u;

  for (int i = tid; i < 2 * 2176; i += 512) hT[i] = 0;
  __syncthreads();
  {  // h(0) i8 into buf0
    int bb = tid >> 6, k0 = (tid & 63) * 4;
    unsigned pk = 0;
#pragma unroll
    for (int i = 0; i < 4; ++i) {
      int q = (int)rintf(inith[(k0 + i) & 127] * 127.f);
      pk |= ((unsigned)(q & 255)) << (8 * i);
    }
    *(unsigned*)&hT[bb * 272 + k0] = pk;
  }
  float c_[2][4];
#pragma unroll
  for (int jt = 0; jt < 2; ++jt)
#pragma unroll
    for (int r = 0; r < 4; ++r) c_[jt][r] = initc[(32 * w + jt * 16 + lk * 4 + r) & 127];

  int4v wq[8][4];
  float sc[8][2];
#pragma unroll
  for (int grp = 0; grp < 8; ++grp) {
    int G = grp >> 1, jt = grp & 1;
    int gb = G * 256 + (w * 2 + jt) * 16;
#pragma unroll
    for (int f = 0; f < 4; ++f)
      wq[grp][f] = *(const int4v*)(wqg + (size_t)(gb + lm) * 64 + f * 16 + lk * 4);
#pragma unroll
    for (int rp = 0; rp < 2; ++rp) sc[grp][rp] = dqp[(gb >> 1) + lk * 2 + rp];
  }
  __syncthreads();

  unsigned Tc0 = 0, Tc1 = 0;
  for (int t = 0; t < LSEQ; ++t) {
    int4v vvi[4], cvi[4];
    if (LAYER == 0) {
      const int4v* vp = (const int4v*)(vpnsw + (size_t)t * 1024 + w * 128 + lk * 32);
#pragma unroll
      for (int q = 0; q < 4; ++q) vvi[q] = vp[q];
#pragma unroll
      for (int q = 0; q < 4; ++q) cvi[q] = (int4v){0, 0, 0, 0};
      int e = eidx[b * LSEQ + t];
      if (e >= 0) {
        const int4v* cp = (const int4v*)(corrsw + (size_t)e * 1024 + w * 128 + lk * 32);
#pragma unroll
        for (int q = 0; q < 4; ++q) cvi[q] = cp[q];
      }
    } else {
      unsigned Tm = (Tc0 < Tc1) ? Tc0 : Tc1;
      while (Tm < (unsigned)(t + 1)) {
        Tc0 = aload(flags + FLAG_H0);
        Tc1 = aload(flags + FLAG_H1);
        Tm = (Tc0 < Tc1) ? Tc0 : Tc1;
        if (--budget == 0) break;
        __builtin_amdgcn_s_sleep(1);
      }
      size_t bse = (size_t)(t & (RINGSZ - 1)) * 2048 + (size_t)(b * 256 + w * 32 + lk * 8);
      unsigned* vd = (unsigned*)vvi;
#pragma unroll
      for (int i = 0; i < 8; ++i) {
        unsigned long long u8 = aload64(uring64 + bse + i);
        vd[2 * i] = (unsigned)u8;
        vd[2 * i + 1] = (unsigned)(u8 >> 32);
      }
#pragma unroll
      for (int q = 0; q < 4; ++q) cvi[q] = (int4v){0, 0, 0, 0};
    }
    const unsigned* vvp = (const unsigned*)vvi;
    const unsigned* cvp = (const unsigned*)cvi;

    const int cur = t & 1;
    int4v bfr[4];
#pragma unroll
    for (int f = 0; f < 4; ++f)
      bfr[f] = *(const int4v*)&hT[cur * 2176 + b * 272 + f * 64 + lk * 16];
    int4v acc[8];
#pragma unroll
    for (int grp = 0; grp < 8; ++grp) {
      acc[grp] = (int4v){0, 0, 0, 0};
#pragma unroll
      for (int f = 0; f < 4; ++f) acc[grp] = MFMAI8(wq[grp][f], bfr[f], acc[grp]);
    }
    // in-register gate/cell/h update; lane holds (b, j=32w+jt*16+lk*4+r)
    float hv[2][4];
#pragma unroll
    for (int jt = 0; jt < 2; ++jt)
#pragma unroll
      for (int r = 0; r < 4; ++r) {
        const int rp = r >> 1, rh = r & 1;
        float g0 = (float)acc[0 + jt][r] * sc[0 + jt][rp] + uph(vvp[(0 + jt) * 2 + rp], rh);
        float g1 = (float)acc[2 + jt][r] * sc[2 + jt][rp] + uph(vvp[(2 + jt) * 2 + rp], rh);
        float g2 = (float)acc[4 + jt][r] * sc[4 + jt][rp] + uph(vvp[(4 + jt) * 2 + rp], rh);
        float g3 = (float)acc[6 + jt][r] * sc[6 + jt][rp] + uph(vvp[(6 + jt) * 2 + rp], rh);
        if (LAYER == 0) {
          g0 += uph(cvp[(0 + jt) * 2 + rp], rh);
          g1 += uph(cvp[(2 + jt) * 2 + rp], rh);
          g2 += uph(cvp[(4 + jt) * 2 + rp], rh);
          g3 += uph(cvp[(6 + jt) * 2 + rp], rh);
        }
        float cn = sigf(g1) * c_[jt][r] + sigf(g0) * tanhf2(g2);
        c_[jt][r] = cn;
        hv[jt][r] = sigf(g3) * tanhf2(cn);
      }
    if (lm < 8) {
      const int nxt = 1 - cur;
#pragma unroll
      for (int jt = 0; jt < 2; ++jt) {
        unsigned pk = 0;
#pragma unroll
        for (int r = 0; r < 4; ++r) {
          int q = (int)rintf(hv[jt][r] * 127.f);
          pk |= ((unsigned)(q & 255)) << (8 * r);
        }
        *(unsigned*)&hT[nxt * 2176 + b * 272 + 32 * w + jt * 16 + lk * 4] = pk;
        if (LAYER == 0) {
          astore(hout + (size_t)(t + 1) * 512 + b * 64 + 8 * w + jt * 4 + lk, pk);
        } else {
          unsigned h01 = (unsigned)f2bf(hv[jt][0]) | ((unsigned)f2bf(hv[jt][1]) << 16);
          unsigned h23 = (unsigned)f2bf(hv[jt][2]) | ((unsigned)f2bf(hv[jt][3]) << 16);
          unsigned* hp = hout + (size_t)(t + 1) * 1024 + b * 128 + 16 * w + jt * 8 + lk * 2;
          astore(hp, h01);
          astore(hp + 1, h23);
        }
      }
    }
    barrier_lgkm();
    if (LAYER == 0) {
      if ((t & 15) == 15) {
        __syncthreads();  // drains vmcnt too
        if (tid == 0) astore(flags + FLAG_R0, (unsigned)(t + 1));
      }
    } else {
      if ((t & 63) == 63 && tid == 0) astore(flags + PROG_R1, (unsigned)(t + 1));
    }
  }
}

static __device__ __forceinline__ void uprod(
    int hid, const unsigned* __restrict__ wqi, const float* __restrict__ dqi,
    unsigned* flags, const unsigned char* __restrict__ h0i, unsigned* uring, int tid) {
  const int w = tid >> 6, l = tid & 63, lm = l & 15, lk = l >> 4, b = lm & 7;
  unsigned budget = 50000000u;
  int4v wq[4][4];
  float sc[4][2];
  int dst[4];
#pragma unroll
  for (int tt = 0; tt < 4; ++tt) {
    int mt = hid * 32 + w * 4 + tt;
#pragma unroll
    for (int f = 0; f < 4; ++f)
      wq[tt][f] = *(const int4v*)(wqi + (size_t)(mt * 16 + lm) * 64 + f * 16 + lk * 4);
#pragma unroll
    for (int rp = 0; rp < 2; ++rp) sc[tt][rp] = dqi[mt * 8 + lk * 2 + rp];
    int G = mt >> 4, jd = mt & 15, wr = jd >> 1, jt = jd & 1, grp = G * 2 + jt;
    dst[tt] = b * 512 + wr * 64 + lk * 16 + grp * 2;
  }
  unsigned Fc = 0, Pc = 0;
  while (Fc < 1u) {
    Fc = aload(flags + FLAG_R0);
    if (--budget == 0) break;
    __builtin_amdgcn_s_sleep(1);
  }
  int4v bnx[4];
#pragma unroll
  for (int f = 0; f < 4; ++f)
    bnx[f] = *(const int4v*)&h0i[(size_t)2048 + b * 256 + f * 64 + lk * 16];
  for (int t = 0; t < LSEQ; ++t) {
    int4v bfr[4];
#pragma unroll
    for (int f = 0; f < 4; ++f) bfr[f] = bnx[f];
    if (t + 1 < LSEQ) {
      while (Fc < (unsigned)(t + 2)) {
        Fc = aload(flags + FLAG_R0);
        if (--budget == 0) break;
        __builtin_amdgcn_s_sleep(1);
      }
      while ((unsigned)(t + 1) >= Pc + (RINGSZ - 128)) {
        Pc = aload(flags + PROG_R1);
        if (--budget == 0) break;
        __builtin_amdgcn_s_sleep(1);
      }
#pragma unroll
      for (int f = 0; f < 4; ++f)
        bnx[f] = *(const int4v*)&h0i[(size_t)(t + 2) * 2048 + b * 256 + f * 64 + lk * 16];
    }
    int4v acc[4];
#pragma unroll
    for (int tt = 0; tt < 4; ++tt) {
      acc[tt] = (int4v){0, 0, 0, 0};
#pragma unroll
      for (int f = 0; f < 4; ++f) acc[tt] = MFMAI8(wq[tt][f], bfr[f], acc[tt]);
    }
    if (lm < 8) {
      int sb = (t & (RINGSZ - 1)) * 4096;
#pragma unroll
      for (int tt = 0; tt < 4; ++tt) {
        float u0 = (float)acc[tt][0] * sc[tt][0];
        float u1 = (float)acc[tt][1] * sc[tt][0];
        float u2 = (float)acc[tt][2] * sc[tt][1];
        float u3 = (float)acc[tt][3] * sc[tt][1];
        astore(uring + sb + dst[tt], (unsigned)f2bf(u0) | ((unsigned)f2bf(u1) << 16));
        astore(uring + sb + dst[tt] + 1, (unsigned)f2bf(u2) | ((unsigned)f2bf(u3) << 16));
      }
    }
    if ((t & 15) == 15) {
      __syncthreads();
      if (tid == 0) astore(flags + (hid ? FLAG_H1 : FLAG_H0), (unsigned)(t + 1));
    }
  }
}

__global__ __launch_bounds__(512, 1) void k_lstm(
    const unsigned* __restrict__ wq0, const float* __restrict__ sc0,
    const unsigned* __restrict__ wq1, const float* __restrict__ sc1,
    const unsigned* __restrict__ wqi, const float* __restrict__ sci,
    const unsigned short* __restrict__ vpnsw, const int* __restrict__ eidx,
    const unsigned short* __restrict__ corrsw,
    const float* __restrict__ inith, const float* __restrict__ initc,
    unsigned* flags, unsigned* uring, unsigned* h0i, unsigned* h1w) {
  __shared__ __align__(16) unsigned char hT[2 * 2176];
  const int tid = threadIdx.x;
  const int bx = blockIdx.x;
  if (bx == 0)
    recur<0>(wq0, sc0, vpnsw, eidx, corrsw, nullptr, inith, initc, flags, h0i, hT, tid);
  else if (bx == 1)
    recur<1>(wq1, sc1, nullptr, nullptr, nullptr, (const unsigned long long*)uring,
             inith, initc, flags, h1w, hT, tid);
  else
    uprod(bx - 2, wqi, sci, flags, (const unsigned char*)h0i, uring, tid);
}

// ---- heads (unchanged) ----
__global__ __launch_bounds__(256, 2) void k_heads(
    const unsigned short* __restrict__ h1u, const float* __restrict__ xadj,
    const float* __restrict__ lgW1, const float* __restrict__ lgb1,
    const float* __restrict__ lgW2, const float* __restrict__ lgb2,
    const float* __restrict__ muW1, const float* __restrict__ mub1,
    const float* __restrict__ muW2, const float* __restrict__ mub2,
    const float* __restrict__ vaW1, const float* __restrict__ vab1,
    const float* __restrict__ vaW2, const float* __restrict__ vab2,
    float* dout) {
  __shared__ float vals[4][3][64];
  const int tid = threadIdx.x;
  const int v = tid >> 6, l = tid & 63, lm = l & 15, lk = l >> 4;
  const int wid = blockIdx.x * 4 + v;
  const int m0 = wid * 64;

  short8 afr[4][8];
#pragma unroll
  for (int tt = 0; tt < 4; ++tt)
#pragma unroll
    for (int ks = 0; ks < 8; ++ks)
      afr[tt][ks] = *(const short8*)(h1u + (size_t)(m0 + tt * 16 + lm) * 256 + 2048 + ks * 32 + lk * 8);

  const float* W1s[3] = {lgW1, muW1, vaW1};
  const float* b1s[3] = {lgb1, mub1, vab1};
  const float* W2s[3] = {lgW2, muW2, vaW2};

  for (int h = 0; h < 3; ++h) {
    float accr[4][4];
#pragma unroll
    for (int tt = 0; tt < 4; ++tt)
#pragma unroll
      for (int r = 0; r < 4; ++r) accr[tt][r] = 0.f;
    const float* W1p = W1s[h];
    const float* b1p = b1s[h];
    const float* W2p = W2s[h];
    for (int nt = 0; nt < 32; ++nt) {
      float4e c0 = {0.f, 0.f, 0.f, 0.f}, c1 = c0, c2 = c0, c3 = c0;
      const float* wp = W1p + (size_t)(nt * 16 + lm) * 256;
#pragma unroll
      for (int ks = 0; ks < 8; ++ks) {
        short8 bfr = pack8f(wp + ks * 32 + lk * 8);
        c0 = MFMA16(afr[0][ks], bfr, c0);
        c1 = MFMA16(afr[1][ks], bfr, c1);
        c2 = MFMA16(afr[2][ks], bfr, c2);
        c3 = MFMA16(afr[3][ks], bfr, c3);
      }
      float bias = b1p[nt * 16 + lm], w2v = W2p[nt * 16 + lm];
#pragma unroll
      for (int r = 0; r < 4; ++r) {
        accr[0][r] += fmaxf(c0[r] + bias, 0.f) * w2v;
        accr[1][r] += fmaxf(c1[r] + bias, 0.f) * w2v;
        accr[2][r] += fmaxf(c2[r] + bias, 0.f) * w2v;
        accr[3][r] += fmaxf(c3[r] + bias, 0.f) * w2v;
      }
    }
#pragma unroll
    for (int tt = 0; tt < 4; ++tt)
#pragma unroll
      for (int r = 0; r < 4; ++r) {
        float a2 = accr[tt][r];
        a2 += __shfl_xor(a2, 1);
        a2 += __shfl_xor(a2, 2);
        a2 += __shfl_xor(a2, 4);
        a2 += __shfl_xor(a2, 8);
        if (lm == 0) vals[v][h][tt * 16 + lk * 4 + r] = a2;
      }
  }
  __syncthreads();
  {
    int m = m0 + l;
    int tq = m >> 3, b = m & 7;
    float z = vals[v][0][l] + lgb2[0];
    float mu = vals[v][1][l] + mub2[0];
    float lv = vals[v][2][l] + vab2[0];
    float x = xadj[(size_t)b * LSEQ + tq];
    float xt = (x > 0.f) ? 1.f : 0.f;
    float lr = fmaxf(z, 0.f) - z * xt + log1pf(expf(-fabsf(z)));
    float lw = 0.f;
    if (x > 0.f) {
      float sm = (x > 20.f) ? x : logf(expm1f(fminf(x, 20.f)));
      float d = mu - sm;
      lw = 0.5f * (lv + d * d * expf(-lv));
    }
#pragma unroll
    for (int d2 = 1; d2 < 64; d2 <<= 1) {
      lr += __shfl_xor(lr, d2);
      lw += __shfl_xor(lw, d2);
    }
    if (l == 0) {
      atomicAdd(dout + 0, lr * (1.f / 1024.f));
      atomicAdd(dout + 1, lw * (1.f / 1024.f));
    }
  }
}

extern "C" void kernel_launch(void* const* d_in, const int* in_sizes, int n_in,
                              void* d_out, int out_size, void* d_ws, size_t ws_size,
                              hipStream_t stream) {
  const float* x_adj = (const float*)d_in[0];
  const float* ee    = (const float*)d_in[1];
  const float* nemb  = (const float*)d_in[2];
  const float* ewW1  = (const float*)d_in[3];
  const float* ewb1  = (const float*)d_in[4];
  const float* ewW2  = (const float*)d_in[5];
  const float* ewb2  = (const float*)d_in[6];
  const float* Wih0  = (const float*)d_in[7];
  const float* Whh0  = (const float*)d_in[8];
  const float* Wih1  = (const float*)d_in[9];
  const float* Whh1  = (const float*)d_in[10];
  const float* muW1  = (const float*)d_in[11];
  const float* mub1  = (const float*)d_in[12];
  const float* muW2  = (const float*)d_in[13];
  const float* mub2  = (const float*)d_in[14];
  const float* vaW1  = (const float*)d_in[15];
  const float* vab1  = (const float*)d_in[16];
  const float* vaW2  = (const float*)d_in[17];
  const float* vab2  = (const float*)d_in[18];
  const float* lgW1  = (const float*)d_in[19];
  const float* lgb1  = (const float*)d_in[20];
  const float* lgW2  = (const float*)d_in[21];
  const float* lgb2  = (const float*)d_in[22];
  const float* inith = (const float*)d_in[23];
  const float* initc = (const float*)d_in[24];

  char* wsb = (char*)d_ws;
  unsigned* flags      = (unsigned*)wsb;
  unsigned* counter    = (unsigned*)(wsb + 512);
  float* P             = (float*)(wsb + WS_P);
  float* aee           = (float*)(wsb + WS_AEE);
  unsigned short* vpnsw = (unsigned short*)(wsb + WS_VPN);
  int* eidx            = (int*)(wsb + WS_EIDX);
  unsigned short* corrsw = (unsigned short*)(wsb + WS_CORR);
  unsigned* wq0        = (unsigned*)(wsb + WS_WQ0);
  float* sc0           = (float*)(wsb + WS_SC0);
  unsigned* wq1        = (unsigned*)(wsb + WS_WQ1);
  float* sc1           = (float*)(wsb + WS_SC1);
  unsigned* wqi        = (unsigned*)(wsb + WS_WQI);
  float* sci           = (float*)(wsb + WS_SCI);
  unsigned* uring      = (unsigned*)(wsb + WS_URING);
  unsigned* h0i        = (unsigned*)(wsb + WS_H0I);
  unsigned* h1w        = (unsigned*)(wsb + WS_H1W);
  unsigned short* h1u  = (unsigned short*)(wsb + WS_H1W);

  (void)in_sizes; (void)n_in; (void)ws_size;

  hipMemsetAsync(d_ws, 0, 4096, stream);
  hipMemsetAsync(d_out, 0, (size_t)out_size * 4, stream);

  k_prep_P<<<512, 256, 0, stream>>>(Wih0, ewW2, P);
  k_prep_aee<<<8, 256, 0, stream>>>(Wih0, ee, ewb1, ewb2, P, aee);
  k_prep_vpn<<<LSEQ, 256, 0, stream>>>(Wih0, nemb, aee, vpnsw);
  k_prep_eidx<<<(NB * LSEQ) / 256, 256, 0, stream>>>(x_adj, eidx, counter);
  k_prep_qw<<<1536, 64, 0, stream>>>(Whh0, Whh1, Wih1, wq0, wq1, wqi, sc0, sc1, sci);
  k_prep_corr<<<NB * LSEQ, 256, 0, stream>>>(x_adj, ewW1, ewb1, P, aee, eidx, corrsw);
  k_lstm<<<4, 512, 0, stream>>>(wq0, sc0, wq1, sc1, wqi, sci, vpnsw, eidx, corrsw,
                                inith, initc, flags, uring, h0i, h1w);
  k_heads<<<254, 256, 0, stream>>>(h1u, x_adj, lgW1, lgb1, lgW2, lgb2,
                                   muW1, mub1, muW2, mub2, vaW1, vab1, vaW2, vab2,
                                   (float*)d_out);
}